// Round 1
// baseline (11405.066 us; speedup 1.0000x reference)
//
#include <hip/hip_runtime.h>

#define TSEQ  784
#define BATCH 256
#define HID   256
#define G4    1024   // 4*HID gate columns
#define DNS   1024
#define NCLS  10

__device__ __forceinline__ float sigmoidf_(float x) {
    return 1.0f / (1.0f + __expf(-x));
}

// Block: 512 threads = 2 batch rows x 256 col-quads (4 consecutive gate cols each).
// The whole T-loop lives inside the kernel; recurrence is block-local.
__global__ __launch_bounds__(512, 1)
void lstm_seq_kernel(const float* __restrict__ X,
                     const float* __restrict__ W_lstm,
                     const float* __restrict__ b_lstm,
                     float* __restrict__ h_out) {
    __shared__ float h_lds[2][HID];
    __shared__ float g_lds[2][G4];

    const int r  = threadIdx.x >> 8;     // 0..1  (batch row within block)
    const int u  = threadIdx.x & 255;    // col-quad id in phase 1 / hidden unit in phase 2
    const int b  = blockIdx.x * 2 + r;
    const int c4 = u * 4;

    const float* Wh = W_lstm + G4;       // rows 1..256 of W_lstm (F=1)

    // t-invariant: Wx row (row 0 of W_lstm) and bias for this thread's 4 cols
    float4 wx = *reinterpret_cast<const float4*>(&W_lstm[c4]);
    float4 bb = *reinterpret_cast<const float4*>(&b_lstm[c4]);

    float ccell = 0.0f;
    h_lds[r][u] = 0.0f;
    __syncthreads();

    const float* Xb = X + b * TSEQ;

    for (int t = 0; t < TSEQ; ++t) {
        const float xv = Xb[t];
        float4 acc;
        acc.x = fmaf(xv, wx.x, bb.x);
        acc.y = fmaf(xv, wx.y, bb.y);
        acc.z = fmaf(xv, wx.z, bb.z);
        acc.w = fmaf(xv, wx.w, bb.w);

        const float* wp = Wh + c4;
        #pragma unroll 4
        for (int k = 0; k < HID; k += 4) {
            float4 h4 = *reinterpret_cast<const float4*>(&h_lds[r][k]);
            float4 w0 = *reinterpret_cast<const float4*>(wp);
            float4 w1 = *reinterpret_cast<const float4*>(wp + G4);
            float4 w2 = *reinterpret_cast<const float4*>(wp + 2 * G4);
            float4 w3 = *reinterpret_cast<const float4*>(wp + 3 * G4);
            acc.x = fmaf(h4.x, w0.x, acc.x);
            acc.y = fmaf(h4.x, w0.y, acc.y);
            acc.z = fmaf(h4.x, w0.z, acc.z);
            acc.w = fmaf(h4.x, w0.w, acc.w);
            acc.x = fmaf(h4.y, w1.x, acc.x);
            acc.y = fmaf(h4.y, w1.y, acc.y);
            acc.z = fmaf(h4.y, w1.z, acc.z);
            acc.w = fmaf(h4.y, w1.w, acc.w);
            acc.x = fmaf(h4.z, w2.x, acc.x);
            acc.y = fmaf(h4.z, w2.y, acc.y);
            acc.z = fmaf(h4.z, w2.z, acc.z);
            acc.w = fmaf(h4.z, w2.w, acc.w);
            acc.x = fmaf(h4.w, w3.x, acc.x);
            acc.y = fmaf(h4.w, w3.y, acc.y);
            acc.z = fmaf(h4.w, w3.z, acc.z);
            acc.w = fmaf(h4.w, w3.w, acc.w);
            wp += 4 * G4;
        }
        *reinterpret_cast<float4*>(&g_lds[r][c4]) = acc;
        __syncthreads();

        // Phase 2: elementwise. Thread (r,u) owns hidden unit u of its row.
        const float gi = g_lds[r][u];
        const float gj = g_lds[r][HID + u];
        const float gf = g_lds[r][2 * HID + u];
        const float go = g_lds[r][3 * HID + u];
        const float ig = sigmoidf_(gi);
        const float jg = tanhf(gj);
        const float fg = sigmoidf_(gf + 1.0f);
        const float og = sigmoidf_(go);
        ccell = fmaf(fg, ccell, ig * jg);
        const float hv = og * tanhf(ccell);
        h_lds[r][u] = hv;
        __syncthreads();
    }

    h_out[b * HID + u] = h_lds[r][u];
}

// One block per batch row: dense = relu(h @ W_dense + b_dense); logits = dense @ W_pred + b_pred
__global__ __launch_bounds__(256, 1)
void head_kernel(const float* __restrict__ h_in,
                 const float* __restrict__ W_dense,
                 const float* __restrict__ b_dense,
                 const float* __restrict__ W_pred,
                 const float* __restrict__ b_pred,
                 float* __restrict__ out) {
    __shared__ float hs[HID];
    __shared__ float ds[DNS];
    __shared__ float red[4];

    const int b = blockIdx.x;
    const int tid = threadIdx.x;

    hs[tid] = h_in[b * HID + tid];
    __syncthreads();

    for (int d = tid; d < DNS; d += 256) {
        float acc = b_dense[d];
        for (int k = 0; k < HID; k += 4) {
            float4 h4 = *reinterpret_cast<const float4*>(&hs[k]);
            acc = fmaf(h4.x, W_dense[(k + 0) * DNS + d], acc);
            acc = fmaf(h4.y, W_dense[(k + 1) * DNS + d], acc);
            acc = fmaf(h4.z, W_dense[(k + 2) * DNS + d], acc);
            acc = fmaf(h4.w, W_dense[(k + 3) * DNS + d], acc);
        }
        ds[d] = fmaxf(acc, 0.0f);
    }
    __syncthreads();

    const int wid = tid >> 6, lane = tid & 63;
    for (int c = 0; c < NCLS; ++c) {
        float p = 0.0f;
        for (int k = tid; k < DNS; k += 256) {
            p = fmaf(ds[k], W_pred[k * NCLS + c], p);
        }
        #pragma unroll
        for (int off = 32; off > 0; off >>= 1) {
            p += __shfl_down(p, off, 64);
        }
        if (lane == 0) red[wid] = p;
        __syncthreads();
        if (tid == 0) {
            out[b * NCLS + c] = red[0] + red[1] + red[2] + red[3] + b_pred[c];
        }
        __syncthreads();
    }
}

extern "C" void kernel_launch(void* const* d_in, const int* in_sizes, int n_in,
                              void* d_out, int out_size, void* d_ws, size_t ws_size,
                              hipStream_t stream) {
    const float* X       = (const float*)d_in[0];
    const float* W_lstm  = (const float*)d_in[1];
    const float* b_lstm  = (const float*)d_in[2];
    const float* W_dense = (const float*)d_in[3];
    const float* b_dense = (const float*)d_in[4];
    const float* W_pred  = (const float*)d_in[5];
    const float* b_pred  = (const float*)d_in[6];
    float* out = (float*)d_out;
    float* h_final = (float*)d_ws;   // 256*256 floats = 256 KB scratch

    lstm_seq_kernel<<<BATCH / 2, 512, 0, stream>>>(X, W_lstm, b_lstm, h_final);
    head_kernel<<<BATCH, 256, 0, stream>>>(h_final, W_dense, b_dense, W_pred, b_pred, out);
}

// Round 2
// 8595.041 us; speedup vs baseline: 1.3269x; 1.3269x over previous
//
#include <hip/hip_runtime.h>
#include <stdint.h>

#define TSEQ  784
#define BATCH 256
#define HID   256
#define DNS   1024
#define NCLS  10

#define UBLK 32   // hidden units per block
#define RBLK 8    // batch rows per block
#define NUS  8    // unit slices
#define NBG  32   // batch groups

__device__ __forceinline__ float sigmoidf_(float x) {
    return 1.0f / (1.0f + __expf(-x));
}
__device__ __forceinline__ float4 fma4(float s, float4 w, float4 a) {
    a.x = fmaf(s, w.x, a.x); a.y = fmaf(s, w.y, a.y);
    a.z = fmaf(s, w.z, a.z); a.w = fmaf(s, w.w, a.w);
    return a;
}
__device__ __forceinline__ float4 add4(float4 a, float4 b) {
    return make_float4(a.x + b.x, a.y + b.y, a.z + b.z, a.w + b.w);
}
__device__ __forceinline__ float4 shfl_xor4(float4 v, int mask) {
    float4 r;
    r.x = __shfl_xor(v.x, mask, 8);
    r.y = __shfl_xor(v.y, mask, 8);
    r.z = __shfl_xor(v.z, mask, 8);
    r.w = __shfl_xor(v.w, mask, 8);
    return r;
}

// Persistent LSTM: 256 blocks = 32 batch-groups x 8 unit-slices.
// Block = 256 threads = 32 units x 8 k-split. Wh slice lives swizzled in LDS.
// Cross-block h exchange via double-buffered hbuf + per-group 8-block barrier.
__global__ __launch_bounds__(256, 1)
void lstm_persist(const float* __restrict__ X,
                  const float* __restrict__ W_lstm,
                  const float* __restrict__ b_lstm,
                  float* __restrict__ hbuf,        // 2 * BATCH*HID floats
                  unsigned int* __restrict__ cnt)  // NBG counters (monotonic)
{
    __shared__ float Wq[256 * UBLK * 4];   // 128 KB, [k][u'][4g], u' XOR-swizzled by k>>5
    __shared__ float hT[64 * 32];          // 8 KB, h_t transposed+swizzled: [k>>2][quad][elem]

    const int tid = threadIdx.x;
    const int u   = tid >> 3;   // 0..31 unit within slice
    const int ks  = tid & 7;    // 0..7 k-split segment (k = ks*32 + ki)

    const int bid = blockIdx.x;
    const int us  = (bid >> 3) & 7;                  // unit slice
    const int bg  = ((bid >> 6) << 3) | (bid & 7);   // batch group; bid%8 == bg%8 -> same XCD per group
    const int ubase = us * UBLK;
    const int rbase = bg * RBLK;

    // ---- one-time: stage Wh slice into LDS, swizzled ----
    for (int idx = tid; idx < 256 * UBLK; idx += 256) {
        const int k  = idx >> 5;
        const int uu = idx & 31;
        const int up = (uu & 24) | ((uu ^ (k >> 5)) & 7);
        float4 w;
        w.x = W_lstm[(1 + k) * 1024 + 0 * 256 + ubase + uu];
        w.y = W_lstm[(1 + k) * 1024 + 1 * 256 + ubase + uu];
        w.z = W_lstm[(1 + k) * 1024 + 2 * 256 + ubase + uu];
        w.w = W_lstm[(1 + k) * 1024 + 3 * 256 + ubase + uu];
        *reinterpret_cast<float4*>(&Wq[k * 128 + up * 4]) = w;
    }
    for (int i = tid; i < 64 * 32; i += 256) hT[i] = 0.0f;   // h_0 = 0

    // t-invariant x-projection weights + bias for this thread's unit (4 gates)
    float4 wx, bb;
    wx.x = W_lstm[0 * 256 + ubase + u];
    wx.y = W_lstm[1 * 256 + ubase + u];
    wx.z = W_lstm[2 * 256 + ubase + u];
    wx.w = W_lstm[3 * 256 + ubase + u];
    bb.x = b_lstm[0 * 256 + ubase + u];
    bb.y = b_lstm[1 * 256 + ubase + u];
    bb.z = b_lstm[2 * 256 + ubase + u];
    bb.w = b_lstm[3 * 256 + ubase + u];

    __syncthreads();

    float c = 0.0f;                               // cell state for (row=ks, unit=u)
    const float* xrow  = X + (rbase + ks) * TSEQ;
    const float* wbase = &Wq[(ks * 32) * 128 + ((u & 24) | ((u ^ ks) & 7)) * 4];
    const int hrowbase = ks * 8 * 32;

    for (int t = 0; t < TSEQ; ++t) {
        float4 acc0 = make_float4(0.f, 0.f, 0.f, 0.f), acc1 = acc0, acc2 = acc0, acc3 = acc0;
        float4 acc4 = acc0, acc5 = acc0, acc6 = acc0, acc7 = acc0;
        const float* wp = wbase;

        #define STEPK(kj) { \
            const int q0 = ((kj) << 1) ^ ks; \
            float4 h0 = *reinterpret_cast<const float4*>(&hT[ro + q0 * 4]); \
            float4 h1 = *reinterpret_cast<const float4*>(&hT[ro + (q0 ^ 1) * 4]); \
            float4 w  = *reinterpret_cast<const float4*>(wp); wp += 128; \
            acc0 = fma4(h0.x, w, acc0); acc1 = fma4(h0.y, w, acc1); \
            acc2 = fma4(h0.z, w, acc2); acc3 = fma4(h0.w, w, acc3); \
            acc4 = fma4(h1.x, w, acc4); acc5 = fma4(h1.y, w, acc5); \
            acc6 = fma4(h1.w * 0.f + h1.z, w, acc6); acc7 = fma4(h1.w, w, acc7); }

        #pragma unroll
        for (int kio = 0; kio < 32; kio += 4) {
            const int ro = hrowbase + (kio >> 2) * 32;
            STEPK(0) STEPK(1) STEPK(2) STEPK(3)
        }
        #undef STEPK

        // ---- k-split reduce-scatter over the 8 ks-lanes (lane ks ends with row ks) ----
        const bool hi4 = (ks & 4) != 0;
        float4 r40 = add4(hi4 ? acc4 : acc0, shfl_xor4(hi4 ? acc0 : acc4, 4));
        float4 r41 = add4(hi4 ? acc5 : acc1, shfl_xor4(hi4 ? acc1 : acc5, 4));
        float4 r42 = add4(hi4 ? acc6 : acc2, shfl_xor4(hi4 ? acc2 : acc6, 4));
        float4 r43 = add4(hi4 ? acc7 : acc3, shfl_xor4(hi4 ? acc3 : acc7, 4));
        const bool hi2 = (ks & 2) != 0;
        float4 r20 = add4(hi2 ? r42 : r40, shfl_xor4(hi2 ? r40 : r42, 2));
        float4 r21 = add4(hi2 ? r43 : r41, shfl_xor4(hi2 ? r41 : r43, 2));
        const bool hi1 = (ks & 1) != 0;
        float4 g4 = add4(hi1 ? r21 : r20, shfl_xor4(hi1 ? r20 : r21, 1));

        // ---- elementwise LSTM cell for (row=ks, unit=u) ----
        const float xv = xrow[t];
        const float gi = g4.x + fmaf(xv, wx.x, bb.x);
        const float gj = g4.y + fmaf(xv, wx.y, bb.y);
        const float gf = g4.z + fmaf(xv, wx.z, bb.z);
        const float go = g4.w + fmaf(xv, wx.w, bb.w);
        c = fmaf(sigmoidf_(gf + 1.0f), c, sigmoidf_(gi) * tanhf(gj));
        const float hval = sigmoidf_(go) * tanhf(c);

        const int nb = (t + 1) & 1;
        __hip_atomic_store(&hbuf[nb * (BATCH * HID) + (rbase + ks) * HID + ubase + u],
                           hval, __ATOMIC_RELAXED, __HIP_MEMORY_SCOPE_AGENT);

        if (t + 1 < TSEQ) {
            __syncthreads();   // all waves' h-stores drained (vmcnt(0) before s_barrier)
            if (tid == 0) {
                const unsigned int tgt = 8u * (unsigned int)(t + 1);
                __hip_atomic_fetch_add(&cnt[bg], 1u, __ATOMIC_ACQ_REL, __HIP_MEMORY_SCOPE_AGENT);
                int guard = 1 << 22;
                while (__hip_atomic_load(&cnt[bg], __ATOMIC_ACQUIRE, __HIP_MEMORY_SCOPE_AGENT) < tgt) {
                    if (--guard == 0) break;  // bounded: placement failure -> wrong answer, not hang
                    __builtin_amdgcn_s_sleep(2);
                }
            }
            __syncthreads();

            // reload full h_{t+1} for our 8 rows into swizzled hT (L1-bypassing loads)
            const int rr = tid & 7;
            const int kb = tid >> 3;
            const float* src = &hbuf[nb * (BATCH * HID) + (rbase + rr) * HID + kb * 8];
            #pragma unroll
            for (int j = 0; j < 8; ++j) {
                const float hv = __hip_atomic_load(&src[j], __ATOMIC_RELAXED, __HIP_MEMORY_SCOPE_AGENT);
                const int k = kb * 8 + j;
                const int q = ((((k & 3) << 1) | (rr >> 2)) ^ ((k >> 5) & 7)) & 7;
                hT[(k >> 2) * 32 + q * 4 + (rr & 3)] = hv;
            }
            __syncthreads();
        }
    }
}

// One block per batch row: dense = relu(h @ W_dense + b); logits = dense @ W_pred + b
__global__ __launch_bounds__(256, 1)
void head_kernel(const float* __restrict__ h_in,
                 const float* __restrict__ W_dense,
                 const float* __restrict__ b_dense,
                 const float* __restrict__ W_pred,
                 const float* __restrict__ b_pred,
                 float* __restrict__ out) {
    __shared__ float hs[HID];
    __shared__ float ds[DNS];
    __shared__ float red[4];

    const int b = blockIdx.x;
    const int tid = threadIdx.x;

    hs[tid] = h_in[b * HID + tid];
    __syncthreads();

    for (int d = tid; d < DNS; d += 256) {
        float acc = b_dense[d];
        for (int k = 0; k < HID; k += 4) {
            float4 h4 = *reinterpret_cast<const float4*>(&hs[k]);
            acc = fmaf(h4.x, W_dense[(k + 0) * DNS + d], acc);
            acc = fmaf(h4.y, W_dense[(k + 1) * DNS + d], acc);
            acc = fmaf(h4.z, W_dense[(k + 2) * DNS + d], acc);
            acc = fmaf(h4.w, W_dense[(k + 3) * DNS + d], acc);
        }
        ds[d] = fmaxf(acc, 0.0f);
    }
    __syncthreads();

    const int wid = tid >> 6, lane = tid & 63;
    for (int c = 0; c < NCLS; ++c) {
        float p = 0.0f;
        for (int k = tid; k < DNS; k += 256) {
            p = fmaf(ds[k], W_pred[k * NCLS + c], p);
        }
        #pragma unroll
        for (int off = 32; off > 0; off >>= 1) {
            p += __shfl_down(p, off, 64);
        }
        if (lane == 0) red[wid] = p;
        __syncthreads();
        if (tid == 0) {
            out[b * NCLS + c] = red[0] + red[1] + red[2] + red[3] + b_pred[c];
        }
        __syncthreads();
    }
}

extern "C" void kernel_launch(void* const* d_in, const int* in_sizes, int n_in,
                              void* d_out, int out_size, void* d_ws, size_t ws_size,
                              hipStream_t stream) {
    const float* X       = (const float*)d_in[0];
    const float* W_lstm  = (const float*)d_in[1];
    const float* b_lstm  = (const float*)d_in[2];
    const float* W_dense = (const float*)d_in[3];
    const float* b_dense = (const float*)d_in[4];
    const float* W_pred  = (const float*)d_in[5];
    const float* b_pred  = (const float*)d_in[6];
    float* out = (float*)d_out;

    float* hbuf = (float*)d_ws;  // 2 * 256*256 floats = 512 KB (double-buffered h)
    unsigned int* cnt = (unsigned int*)((char*)d_ws + 2 * BATCH * HID * sizeof(float));

    hipMemsetAsync(cnt, 0, NBG * sizeof(unsigned int), stream);
    lstm_persist<<<NBG * NUS, 256, 0, stream>>>(X, W_lstm, b_lstm, hbuf, cnt);
    // final h (h_784) lands in buffer 0 = start of hbuf
    head_kernel<<<BATCH, 256, 0, stream>>>(hbuf, W_dense, b_dense, W_pred, b_pred, out);
}

// Round 3
// 4907.558 us; speedup vs baseline: 2.3240x; 1.7514x over previous
//
#include <hip/hip_runtime.h>
#include <stdint.h>

#define TSEQ  784
#define BATCH 256
#define HID   256
#define DNS   1024
#define NCLS  10

#define NBG  32   // batch groups (8 rows each)
#define NUS  8    // unit slices (32 units each)
#define RBLK 8

__device__ __forceinline__ float sigmoidf_(float x) {
    return 1.0f / (1.0f + __expf(-x));
}
__device__ __forceinline__ float tanhf_(float x) {
    float ax = fabsf(x);
    float e  = __expf(2.0f * ax);
    float r  = 1.0f - 2.0f / (e + 1.0f);
    return copysignf(r, x);
}
__device__ __forceinline__ float4 fma4(float s, float4 w, float4 a) {
    a.x = fmaf(s, w.x, a.x); a.y = fmaf(s, w.y, a.y);
    a.z = fmaf(s, w.z, a.z); a.w = fmaf(s, w.w, a.w);
    return a;
}
__device__ __forceinline__ float4 add4(float4 a, float4 b) {
    return make_float4(a.x + b.x, a.y + b.y, a.z + b.z, a.w + b.w);
}
__device__ __forceinline__ float4 shfl_xor4(float4 v, int m) {
    float4 r;
    r.x = __shfl_xor(v.x, m, 64);
    r.y = __shfl_xor(v.y, m, 64);
    r.z = __shfl_xor(v.z, m, 64);
    r.w = __shfl_xor(v.w, m, 64);
    return r;
}

// Persistent LSTM: 256 blocks = 32 batch-groups x 8 unit-slices, 512 thr/block.
// Thread (u = tid>>4, ks = tid&15): unit u of slice, k-segment [ks*16, ks*16+16).
// Weights in LDS (swizzled), h_t in LDS (f4-XOR swizzled), reduce via shfl,
// cross-block exchange through fabric with RELAXED atomics only.
__global__ __launch_bounds__(512, 1)
void lstm_persist(const float* __restrict__ X,
                  const float* __restrict__ W_lstm,
                  const float* __restrict__ b_lstm,
                  float* __restrict__ hbuf,        // 2 * BATCH*HID floats
                  unsigned int* __restrict__ cnt)  // NBG counters (monotonic)
{
    __shared__ float Wq[256 * 128];   // 128 KB: f4 [k][u_p], float idx = k*128 + u_p*4
    __shared__ float hT[512 * 4];     // 8 KB:  f4 idx = (k*2+rh) ^ ((k>>4)&7), elem = row&3

    const int tid = threadIdx.x;
    const int u   = tid >> 4;    // 0..31
    const int ks  = tid & 15;    // 0..15

    const int bid = blockIdx.x;
    const int us  = (bid >> 3) & 7;
    const int bg  = ((bid >> 6) << 3) | (bid & 7);
    const int ubase = us * 32;
    const int rbase = bg * RBLK;

    // ---- one-time: stage Wh slice into LDS (swizzled by k>>4) ----
    for (int idx = tid; idx < 256 * 32; idx += 512) {
        const int k  = idx >> 5;
        const int uu = idx & 31;
        const int up = (uu & 24) | ((uu ^ (k >> 4)) & 7);
        float4 w;
        w.x = W_lstm[(1 + k) * 1024 + 0 * 256 + ubase + uu];
        w.y = W_lstm[(1 + k) * 1024 + 1 * 256 + ubase + uu];
        w.z = W_lstm[(1 + k) * 1024 + 2 * 256 + ubase + uu];
        w.w = W_lstm[(1 + k) * 1024 + 3 * 256 + ubase + uu];
        *reinterpret_cast<float4*>(&Wq[k * 128 + up * 4]) = w;
    }
    for (int i = tid; i < 512 * 4; i += 512) hT[i] = 0.0f;   // h_0 = 0

    // t-invariant x-projection weights + bias for unit u (4 gates)
    float4 wx, bb;
    wx.x = W_lstm[0 * 256 + ubase + u];
    wx.y = W_lstm[1 * 256 + ubase + u];
    wx.z = W_lstm[2 * 256 + ubase + u];
    wx.w = W_lstm[3 * 256 + ubase + u];
    bb.x = b_lstm[0 * 256 + ubase + u];
    bb.y = b_lstm[1 * 256 + ubase + u];
    bb.z = b_lstm[2 * 256 + ubase + u];
    bb.w = b_lstm[3 * 256 + ubase + u];

    __syncthreads();

    const int row = ks >> 1;                 // this thread's batch row (pair-redundant)
    float c = 0.0f;                          // cell state for (row, unit u)
    const float* xrow = X + (rbase + row) * TSEQ;
    const int s    = ks & 7;                 // hT swizzle key (== (k>>4)&7 for our k's)
    const int up4  = ((u & 24) | ((u ^ ks) & 7)) * 4;
    const int kbase = ks * 16;

    for (int t = 0; t < TSEQ; ++t) {
        const float xv = xrow[t];

        float4 a0 = make_float4(0,0,0,0), a1 = a0, a2 = a0, a3 = a0;
        float4 a4 = a0, a5 = a0, a6 = a0, a7 = a0;

        #pragma unroll 8
        for (int ki = 0; ki < 16; ++ki) {
            const int k = kbase + ki;
            float4 w  = *reinterpret_cast<const float4*>(&Wq[k * 128 + up4]);
            float4 h0 = *reinterpret_cast<const float4*>(&hT[(((k << 1)    ) ^ s) << 2]);
            float4 h1 = *reinterpret_cast<const float4*>(&hT[(((k << 1) | 1) ^ s) << 2]);
            a0 = fma4(h0.x, w, a0); a1 = fma4(h0.y, w, a1);
            a2 = fma4(h0.z, w, a2); a3 = fma4(h0.w, w, a3);
            a4 = fma4(h1.x, w, a4); a5 = fma4(h1.y, w, a5);
            a6 = fma4(h1.z, w, a6); a7 = fma4(h1.w, w, a7);
        }

        // ---- reduce-scatter over the 16 ks-lanes: lane ks -> row ks>>1 (pairs redundant) ----
        const bool h8 = (ks & 8) != 0;
        float4 b0 = add4(h8 ? a4 : a0, shfl_xor4(h8 ? a0 : a4, 8));
        float4 b1 = add4(h8 ? a5 : a1, shfl_xor4(h8 ? a1 : a5, 8));
        float4 b2 = add4(h8 ? a6 : a2, shfl_xor4(h8 ? a2 : a6, 8));
        float4 b3 = add4(h8 ? a7 : a3, shfl_xor4(h8 ? a3 : a7, 8));
        const bool h4 = (ks & 4) != 0;
        float4 c0 = add4(h4 ? b2 : b0, shfl_xor4(h4 ? b0 : b2, 4));
        float4 c1 = add4(h4 ? b3 : b1, shfl_xor4(h4 ? b1 : b3, 4));
        const bool h2 = (ks & 2) != 0;
        float4 d0 = add4(h2 ? c1 : c0, shfl_xor4(h2 ? c0 : c1, 2));
        float4 g  = add4(d0, shfl_xor4(d0, 1));   // both lanes of pair: full 4-gate sum

        // ---- elementwise LSTM cell for (row, u) ----
        const float gi = g.x + fmaf(xv, wx.x, bb.x);
        const float gj = g.y + fmaf(xv, wx.y, bb.y);
        const float gf = g.z + fmaf(xv, wx.z, bb.z);
        const float go = g.w + fmaf(xv, wx.w, bb.w);
        c = fmaf(sigmoidf_(gf + 1.0f), c, sigmoidf_(gi) * tanhf_(gj));
        const float hval = sigmoidf_(go) * tanhf_(c);

        const int nb = (t + 1) & 1;
        float* hb = hbuf + nb * (BATCH * HID);
        if ((ks & 1) == 0) {
            __hip_atomic_store(&hb[(rbase + row) * HID + ubase + u], hval,
                               __ATOMIC_RELAXED, __HIP_MEMORY_SCOPE_AGENT);
        }

        if (t + 1 < TSEQ) {
            __syncthreads();   // drains vmcnt(0): h-stores at fabric before flag add
            if (tid == 0) {
                const unsigned int tgt = 8u * (unsigned int)(t + 1);
                __hip_atomic_fetch_add(&cnt[bg], 1u, __ATOMIC_RELAXED, __HIP_MEMORY_SCOPE_AGENT);
                int guard = 1 << 22;
                while (__hip_atomic_load(&cnt[bg], __ATOMIC_RELAXED, __HIP_MEMORY_SCOPE_AGENT) < tgt) {
                    if (--guard == 0) break;  // bounded: never hang
                    __builtin_amdgcn_s_sleep(1);
                }
            }
            __syncthreads();

            // reload h_{t+1}: 2048 floats, 4 per thread, coalesced 16B/lane pattern
            const int rrow = tid >> 6;
            const int k0   = (tid & 63) * 4;
            const float* src = hb + (rbase + rrow) * HID + k0;
            const int rh = rrow >> 2, re = rrow & 3;
            #pragma unroll
            for (int j = 0; j < 4; ++j) {
                const float hv = __hip_atomic_load(&src[j], __ATOMIC_RELAXED, __HIP_MEMORY_SCOPE_AGENT);
                const int k = k0 + j;
                const int f4s = ((k * 2 + rh) ^ ((k >> 4) & 7));
                hT[f4s * 4 + re] = hv;
            }
            __syncthreads();
        }
    }
}

// One block per batch row: dense = relu(h @ W_dense + b); logits = dense @ W_pred + b
__global__ __launch_bounds__(256, 1)
void head_kernel(const float* __restrict__ h_in,
                 const float* __restrict__ W_dense,
                 const float* __restrict__ b_dense,
                 const float* __restrict__ W_pred,
                 const float* __restrict__ b_pred,
                 float* __restrict__ out) {
    __shared__ float hs[HID];
    __shared__ float ds[DNS];
    __shared__ float red[4];

    const int b = blockIdx.x;
    const int tid = threadIdx.x;

    hs[tid] = __hip_atomic_load(&h_in[b * HID + tid], __ATOMIC_RELAXED, __HIP_MEMORY_SCOPE_AGENT);
    __syncthreads();

    for (int d = tid; d < DNS; d += 256) {
        float acc = b_dense[d];
        for (int k = 0; k < HID; k += 4) {
            float4 h4 = *reinterpret_cast<const float4*>(&hs[k]);
            acc = fmaf(h4.x, W_dense[(k + 0) * DNS + d], acc);
            acc = fmaf(h4.y, W_dense[(k + 1) * DNS + d], acc);
            acc = fmaf(h4.z, W_dense[(k + 2) * DNS + d], acc);
            acc = fmaf(h4.w, W_dense[(k + 3) * DNS + d], acc);
        }
        ds[d] = fmaxf(acc, 0.0f);
    }
    __syncthreads();

    const int wid = tid >> 6, lane = tid & 63;
    for (int c = 0; c < NCLS; ++c) {
        float p = 0.0f;
        for (int k = tid; k < DNS; k += 256) {
            p = fmaf(ds[k], W_pred[k * NCLS + c], p);
        }
        #pragma unroll
        for (int off = 32; off > 0; off >>= 1) {
            p += __shfl_down(p, off, 64);
        }
        if (lane == 0) red[wid] = p;
        __syncthreads();
        if (tid == 0) {
            out[b * NCLS + c] = red[0] + red[1] + red[2] + red[3] + b_pred[c];
        }
        __syncthreads();
    }
}

extern "C" void kernel_launch(void* const* d_in, const int* in_sizes, int n_in,
                              void* d_out, int out_size, void* d_ws, size_t ws_size,
                              hipStream_t stream) {
    const float* X       = (const float*)d_in[0];
    const float* W_lstm  = (const float*)d_in[1];
    const float* b_lstm  = (const float*)d_in[2];
    const float* W_dense = (const float*)d_in[3];
    const float* b_dense = (const float*)d_in[4];
    const float* W_pred  = (const float*)d_in[5];
    const float* b_pred  = (const float*)d_in[6];
    float* out = (float*)d_out;

    float* hbuf = (float*)d_ws;  // 2 * 256*256 floats = 512 KB
    unsigned int* cnt = (unsigned int*)((char*)d_ws + 2 * BATCH * HID * sizeof(float));

    hipMemsetAsync(cnt, 0, NBG * sizeof(unsigned int), stream);
    lstm_persist<<<NBG * NUS, 512, 0, stream>>>(X, W_lstm, b_lstm, hbuf, cnt);
    // h_784 lands in buffer 0 (784 is even)
    head_kernel<<<BATCH, 256, 0, stream>>>(hbuf, W_dense, b_dense, W_pred, b_pred, out);
}